// Round 3
// baseline (156.003 us; speedup 1.0000x reference)
//
#include <hip/hip_runtime.h>
#include <hip/hip_bf16.h>

#define BB 16
#define NN 1024
#define CC 256

typedef __attribute__((ext_vector_type(8))) short bf16x8;
typedef __attribute__((ext_vector_type(4))) short s16x4;
typedef __attribute__((ext_vector_type(4))) float f32x4;

#define GPTR(p) ((const __attribute__((address_space(1))) void*)(p))
#define LPTR(p) ((__attribute__((address_space(3))) void*)(p))

__device__ __forceinline__ unsigned short f2bf(float f) {
  union { float f; unsigned u; } v; v.f = f;
  unsigned r = v.u + 0x7FFFu + ((v.u >> 16) & 1u);
  return (unsigned short)(r >> 16);
}

// Merged preprocessing: blocks [0, NCAST) cast x/W/b; blocks [NCAST, +1024)
// transpose Wp -> Amat.
#define NCAST 17155
__global__ __launch_bounds__(256) void preprocess(
    const float* __restrict__ x,
    const float* __restrict__ Wq, const float* __restrict__ Wk,
    const float* __restrict__ Wv,
    const float* __restrict__ bq, const float* __restrict__ bk,
    const float* __restrict__ bv,
    const float* __restrict__ Wp,
    unsigned short* __restrict__ xb,
    unsigned short* __restrict__ wqkvb,
    float* __restrict__ bqkv,
    unsigned short* __restrict__ Amat) {
  __shared__ float tile[32][33];
  int blk = blockIdx.x;
  if (blk < NCAST) {
    const int NX = BB * NN * CC;
    const int NW = CC * CC;
    int i = blk * 256 + threadIdx.x;
    if (i < NX) { xb[i] = f2bf(x[i]); return; }
    int j = i - NX;
    if (j < 3 * NW) {
      const float* w = (j < NW) ? Wq : (j < 2 * NW ? Wk : Wv);
      wqkvb[j] = f2bf(w[j % NW]);
      return;
    }
    int jj = j - 3 * NW;
    if (jj < 3 * CC) {
      const float* bb = (jj < CC) ? bq : (jj < 2 * CC ? bk : bv);
      bqkv[jj] = bb[jj % CC];
    }
    return;
  }
  int wb = blk - NCAST;          // 0..1023
  int h = wb >> 5;
  int n0 = (wb & 31) * 32;
#pragma unroll
  for (int j = 0; j < 4; j++) {
    int idx = threadIdx.x + j * 256;
    int a = idx >> 5, wc = idx & 31;
    tile[a][wc] = Wp[(size_t)h * (NN * 32) + (size_t)(n0 + a) * 32 + wc];
  }
  __syncthreads();
#pragma unroll
  for (int j = 0; j < 4; j++) {
    int idx = threadIdx.x + j * 256;
    int wc = idx >> 5, a = idx & 31;
    Amat[(size_t)(h * 32 + wc) * NN + n0 + a] = f2bf(tile[a][wc]);
  }
}

// Tiled GEMM: C[m][n] = sum_k A[m][k]*Bt[n][k]. BM=128 BN=64 BK=64.
// Grid: (batch, m-tiles, n-tiles)  [batch on x => XCD affinity]
template <int BIAS_MODE, int F32OUT>
__global__ __launch_bounds__(256) void gemm_tile(
    const unsigned short* __restrict__ A, int lda, long sA,
    const unsigned short* __restrict__ Bt, int ldb, long sB,
    const float* __restrict__ bias,
    void* __restrict__ Out, int ldo, long sO, int K) {
  __shared__ unsigned short As[2 * 128 * 32];
  __shared__ unsigned short Bs[2 * 64 * 32];
  int b = blockIdx.x;
  int m0 = blockIdx.y * 128;
  int n0 = blockIdx.z * 64;
  int t = threadIdx.x;
  int w = t >> 6, lane = t & 63;
  int wm = (w >> 1) * 64, wn = (w & 1) * 32;
  int r = lane & 15, g = lane >> 4;

  const unsigned short* Ab = A + (long)b * sA;
  const unsigned short* Bb = Bt + (long)b * sB;

  int srow = t >> 2;
  int scol = (t & 3) * 8;

  f32x4 acc[4][2];
#pragma unroll
  for (int i = 0; i < 4; i++)
#pragma unroll
    for (int j = 0; j < 2; j++) acc[i][j] = (f32x4){0.f, 0.f, 0.f, 0.f};

  for (int k0 = 0; k0 < K; k0 += 64) {
    __syncthreads();
#pragma unroll
    for (int kh = 0; kh < 2; kh++) {
#pragma unroll
      for (int jj = 0; jj < 2; jj++) {
        __builtin_amdgcn_global_load_lds(
            GPTR(Ab + (long)(m0 + srow + jj * 64) * lda + k0 + kh * 32 + scol),
            LPTR(&As[kh * 4096 + jj * 2048 + t * 8]), 16, 0, 0);
      }
      __builtin_amdgcn_global_load_lds(
          GPTR(Bb + (long)(n0 + srow) * ldb + k0 + kh * 32 + scol),
          LPTR(&Bs[kh * 2048 + t * 8]), 16, 0, 0);
    }
    __syncthreads();
#pragma unroll
    for (int kh = 0; kh < 2; kh++) {
      bf16x8 af[4], bfr[2];
#pragma unroll
      for (int ti = 0; ti < 4; ti++)
        af[ti] = *(const bf16x8*)&As[kh * 4096 + (wm + ti * 16 + r) * 32 + g * 8];
#pragma unroll
      for (int tj = 0; tj < 2; tj++)
        bfr[tj] = *(const bf16x8*)&Bs[kh * 2048 + (wn + tj * 16 + r) * 32 + g * 8];
#pragma unroll
      for (int ti = 0; ti < 4; ti++)
#pragma unroll
        for (int tj = 0; tj < 2; tj++)
          acc[ti][tj] = __builtin_amdgcn_mfma_f32_16x16x32_bf16(af[ti], bfr[tj], acc[ti][tj], 0, 0, 0);
    }
  }

#pragma unroll
  for (int ti = 0; ti < 4; ti++) {
#pragma unroll
    for (int tj = 0; tj < 2; tj++) {
      int col = n0 + wn + tj * 16 + r;
      float bc = (BIAS_MODE == 1) ? bias[col] : 0.0f;
#pragma unroll
      for (int rr = 0; rr < 4; rr++) {
        int row = m0 + wm + ti * 16 + g * 4 + rr;
        float val = acc[ti][tj][rr] + bc;
        long oidx = (long)b * sO + (long)row * ldo + col;
        if (F32OUT)
          ((float*)Out)[oidx] = val;
        else
          ((unsigned short*)Out)[oidx] = f2bf(val);
      }
    }
  }
}

// Fused QKV projection, 128x128 tile, BK=64 (two k-panels, 8 barriers).
// Grid: (batch, 8 m-tiles, 6 n-tiles of 128).  3 blocks/CU.
// K written TILED: Kt[c>>5][tok][c&31]; V TILED: V5[c>>4][m>>3][c&15][m&7].
__global__ __launch_bounds__(256) void gemm_qkv(
    const unsigned short* __restrict__ A,
    const unsigned short* __restrict__ Bt,
    const float* __restrict__ bias,
    unsigned short* __restrict__ Qb, unsigned short* __restrict__ Kb,
    unsigned short* __restrict__ Vtb) {
  __shared__ unsigned short As[2 * 128 * 32];  // 16 KB
  __shared__ unsigned short Bs[2 * 128 * 32];  // 16 KB
  int b = blockIdx.x;
  int m0 = blockIdx.y * 128;
  int n0 = blockIdx.z * 128;
  int t = threadIdx.x;
  int w = t >> 6, lane = t & 63;
  int wm = (w >> 1) * 64, wn = (w & 1) * 64;
  int r = lane & 15, g = lane >> 4;

  const unsigned short* Ab = A + (long)b * NN * CC;
  int srow = t >> 2;            // 0..63
  int scol = (t & 3) * 8;

  f32x4 acc[4][4];
#pragma unroll
  for (int i = 0; i < 4; i++)
#pragma unroll
    for (int j = 0; j < 4; j++) acc[i][j] = (f32x4){0.f, 0.f, 0.f, 0.f};

  for (int k0 = 0; k0 < CC; k0 += 64) {
    __syncthreads();
#pragma unroll
    for (int kh = 0; kh < 2; kh++) {
#pragma unroll
      for (int jj = 0; jj < 2; jj++) {
        __builtin_amdgcn_global_load_lds(
            GPTR(Ab + (long)(m0 + srow + jj * 64) * CC + k0 + kh * 32 + scol),
            LPTR(&As[kh * 4096 + jj * 2048 + t * 8]), 16, 0, 0);
        __builtin_amdgcn_global_load_lds(
            GPTR(Bt + (long)(n0 + srow + jj * 64) * CC + k0 + kh * 32 + scol),
            LPTR(&Bs[kh * 4096 + jj * 2048 + t * 8]), 16, 0, 0);
      }
    }
    __syncthreads();
#pragma unroll
    for (int kh = 0; kh < 2; kh++) {
      bf16x8 af[4], bfr[4];
#pragma unroll
      for (int ti = 0; ti < 4; ti++)
        af[ti] = *(const bf16x8*)&As[kh * 4096 + (wm + ti * 16 + r) * 32 + g * 8];
#pragma unroll
      for (int tj = 0; tj < 4; tj++)
        bfr[tj] = *(const bf16x8*)&Bs[kh * 4096 + (wn + tj * 16 + r) * 32 + g * 8];
#pragma unroll
      for (int ti = 0; ti < 4; ti++)
#pragma unroll
        for (int tj = 0; tj < 4; tj++)
          acc[ti][tj] = __builtin_amdgcn_mfma_f32_16x16x32_bf16(af[ti], bfr[tj], acc[ti][tj], 0, 0, 0);
    }
  }

  int seg = n0 >> 8;   // 128-col span stays within one 256-col segment
#pragma unroll
  for (int ti = 0; ti < 4; ti++) {
#pragma unroll
    for (int tj = 0; tj < 4; tj++) {
      int col = n0 + wn + tj * 16 + r;
      int c = col & 255;
      float bc = bias[col];
#pragma unroll
      for (int rr = 0; rr < 4; rr++) {
        int row = m0 + wm + ti * 16 + g * 4 + rr;   // token index
        float val = acc[ti][tj][rr] + bc;
        long base = (long)b * NN * CC;
        if (seg == 0) {
          Qb[base + (long)row * CC + c] = f2bf(val);
        } else if (seg == 1) {
          Kb[base + ((long)(c >> 5) * NN + row) * 32 + (c & 31)] = f2bf(val);
        } else {
          Vtb[base + ((((long)(c >> 4) * 128 + (row >> 3)) * 16 + (c & 15)) * 8 + (row & 7))] = f2bf(val);
        }
      }
    }
  }
}

// Fused scores+softmax+PV v11. 512 thr = 8 waves; 64 Q-rows/block.
// Grid (batch, 16) = 256 blocks = 1/CU; all blocks of batch b land on
// XCD b%8 (bid%8 == b%8) -> K/V L2-resident, re-read 16x not 32x.
// Phase 1 (QK^T): BARRIER-FREE double-buffered DMA pipeline. Each wave owns
//   tokens [w*128,+128) exclusively, stages its own 8 KB K-slice per slab
//   via global_load_lds into alternating 64 KB buffers, and synchronizes
//   only with counted `s_waitcnt vmcnt(8)` (slab k+1 stays in flight while
//   slab k computes). No __syncthreads until softmax.
// Phase 2: softmax, 8-wave combine via red[8][64]; P bf16 -> LDS (128 KB,
//   overlays both K buffers; safe: first red barrier orders it after all
//   K reads), chunk-XOR swizzle prow&7.
// Phase 3: O = P V, V streamed from tiled V5 (L2), unroll 4.
// Epilogue: direct s16x4 stores; 64 rows => full 128B line per c per block.
__global__ __launch_bounds__(512, 2) void attn_fused(
    const unsigned short* __restrict__ Q,    // [B][1024][256]
    const unsigned short* __restrict__ Kt,   // [B][8][1024][32] tiled
    const unsigned short* __restrict__ Vt,   // [B] tiled V5
    unsigned short* __restrict__ QKVt) {     // [B][256][1024]
  __shared__ unsigned short ShBuf[64 * 1024];  // 128 KB: 2x64KB K slabs, then P[64][1024]
  __shared__ float red[8][64];
  int b = blockIdx.x;
  int n0 = blockIdx.y * 64;
  int t = threadIdx.x;
  int w = t >> 6, lane = t & 63;
  int r = lane & 15, g = lane >> 4;

  // wave-private K slice: tokens [w*128, +128), 32 ch per slab, 8 KB
  const unsigned short* kslab = Kt + (long)b * NN * CC + w * 128 * 32;
  unsigned short* wbuf0 = &ShBuf[w * 4096];           // 8 KB slice in buffer 0
  unsigned short* wbuf1 = &ShBuf[32768 + w * 4096];   // 8 KB slice in buffer 1

  const unsigned short* qbase = Q + ((long)b * NN + n0 + r) * CC + g * 8;

  // prologue: stage slab 0 (own slice), load q-frags slab 0
#pragma unroll
  for (int j = 0; j < 8; j++)
    __builtin_amdgcn_global_load_lds(GPTR(kslab + j * 512 + lane * 8),
                                     LPTR(wbuf0 + j * 512 + lane * 8), 16, 0, 0);
  bf16x8 qa[4];
#pragma unroll
  for (int rt = 0; rt < 4; rt++)
    qa[rt] = *(const bf16x8*)(qbase + rt * 16 * CC);

  f32x4 acc[4][8];
#pragma unroll
  for (int i = 0; i < 4; i++)
#pragma unroll
    for (int j = 0; j < 8; j++) acc[i][j] = (f32x4){0.f, 0.f, 0.f, 0.f};

#pragma unroll
  for (int kk = 0; kk < 8; kk++) {
    unsigned short* cur = (kk & 1) ? wbuf1 : wbuf0;
    unsigned short* nxt = (kk & 1) ? wbuf0 : wbuf1;
    if (kk < 7) {
      const unsigned short* src = kslab + (long)(kk + 1) * (NN * 32);
#pragma unroll
      for (int j = 0; j < 8; j++)
        __builtin_amdgcn_global_load_lds(GPTR(src + j * 512 + lane * 8),
                                         LPTR(nxt + j * 512 + lane * 8), 16, 0, 0);
      asm volatile("s_waitcnt vmcnt(8)" ::: "memory");  // slab kk landed; kk+1 in flight
    } else {
      asm volatile("s_waitcnt vmcnt(0)" ::: "memory");
    }
    __builtin_amdgcn_sched_barrier(0);
    bf16x8 qn[4];
    if (kk < 7) {
#pragma unroll
      for (int rt = 0; rt < 4; rt++)
        qn[rt] = *(const bf16x8*)(qbase + (kk + 1) * 32 + rt * 16 * CC);
    }
#pragma unroll
    for (int ct = 0; ct < 8; ct++) {
      bf16x8 kf = *(const bf16x8*)&cur[(ct * 16 + r) * 32 + g * 8];
#pragma unroll
      for (int rt = 0; rt < 4; rt++)
        acc[rt][ct] = __builtin_amdgcn_mfma_f32_16x16x32_bf16(qa[rt], kf, acc[rt][ct], 0, 0, 0);
    }
    if (kk < 7) {
#pragma unroll
      for (int rt = 0; rt < 4; rt++) qa[rt] = qn[rt];
    }
    __builtin_amdgcn_sched_barrier(0);  // pin cross-iteration order (stage vs prior reads)
  }

  // ---- softmax ----  acc[rt][ct][rr]: row = rt*16+g*4+rr, col = w*128+ct*16+r
  float mrow[4][4];
#pragma unroll
  for (int rt = 0; rt < 4; rt++) {
#pragma unroll
    for (int rr = 0; rr < 4; rr++) {
      float m = acc[rt][0][rr];
#pragma unroll
      for (int ct = 1; ct < 8; ct++) m = fmaxf(m, acc[rt][ct][rr]);
#pragma unroll
      for (int d = 1; d < 16; d <<= 1) m = fmaxf(m, __shfl_xor(m, d, 64));
      mrow[rt][rr] = m;
    }
  }
  if (r == 0) {
#pragma unroll
    for (int rt = 0; rt < 4; rt++)
#pragma unroll
      for (int rr = 0; rr < 4; rr++)
        red[w][rt * 16 + g * 4 + rr] = mrow[rt][rr];
  }
  __syncthreads();   // #1: also orders all phase-1 K reads before P writes below
#pragma unroll
  for (int rt = 0; rt < 4; rt++) {
#pragma unroll
    for (int rr = 0; rr < 4; rr++) {
      int row = rt * 16 + g * 4 + rr;
      float m = red[0][row];
#pragma unroll
      for (int w2 = 1; w2 < 8; w2++) m = fmaxf(m, red[w2][row]);
      mrow[rt][rr] = m;
    }
  }
  __syncthreads();   // #2: WAR before sum overwrites red
  float ssum[4][4];
#pragma unroll
  for (int rt = 0; rt < 4; rt++) {
#pragma unroll
    for (int rr = 0; rr < 4; rr++) {
      float s = 0.f;
#pragma unroll
      for (int ct = 0; ct < 8; ct++) {
        float e = exp2f((acc[rt][ct][rr] - mrow[rt][rr]) * 1.44269504088896f);
        acc[rt][ct][rr] = e;
        s += e;
      }
#pragma unroll
      for (int d = 1; d < 16; d <<= 1) s += __shfl_xor(s, d, 64);
      ssum[rt][rr] = s;
    }
  }
  if (r == 0) {
#pragma unroll
    for (int rt = 0; rt < 4; rt++)
#pragma unroll
      for (int rr = 0; rr < 4; rr++)
        red[w][rt * 16 + g * 4 + rr] = ssum[rt][rr];
  }
  __syncthreads();   // #3
  // ---- phase 2: P -> LDS (overlays K buffers), chunk-XOR swizzle (prow&7) ----
#pragma unroll
  for (int rt = 0; rt < 4; rt++) {
#pragma unroll
    for (int rr = 0; rr < 4; rr++) {
      int prow = rt * 16 + g * 4 + rr;
      float s = 0.f;
#pragma unroll
      for (int w2 = 0; w2 < 8; w2++) s += red[w2][prow];
      float inv = 1.0f / s;
      int sw = prow & 7;
#pragma unroll
      for (int ct = 0; ct < 8; ct++) {
        int col = w * 128 + ct * 16 + r;
        int chunk = (col >> 3) ^ sw;
        ShBuf[prow * 1024 + chunk * 8 + (col & 7)] = f2bf(acc[rt][ct][rr] * inv);
      }
    }
  }
  __syncthreads();   // #4

  // ---- phase 3: O = P V.  Wave w owns O cols [w*32,+32), rows n0..n0+64.
  const unsigned short* vbase = Vt + (long)b * NN * CC;  // tiled V5
  int cw = w * 32;
  f32x4 o[4][2];
#pragma unroll
  for (int i = 0; i < 4; i++)
#pragma unroll
    for (int j = 0; j < 2; j++) o[i][j] = (f32x4){0.f, 0.f, 0.f, 0.f};

#pragma unroll 4
  for (int m0 = 0; m0 < NN; m0 += 32) {
    bf16x8 ar[4], br[2];
#pragma unroll
    for (int bt = 0; bt < 2; bt++) {
      long vidx = (((long)((cw >> 4) + bt) * 128 + (m0 >> 3) + g) * 16 + r) * 8;
      br[bt] = *(const bf16x8*)(vbase + vidx);
    }
#pragma unroll
    for (int rt = 0; rt < 4; rt++) {
      int prow = rt * 16 + r;
      int chunk = ((m0 >> 3) + g) ^ (prow & 7);
      ar[rt] = *(const bf16x8*)&ShBuf[prow * 1024 + chunk * 8];
    }
#pragma unroll
    for (int rt = 0; rt < 4; rt++)
#pragma unroll
      for (int bt = 0; bt < 2; bt++)
        o[rt][bt] = __builtin_amdgcn_mfma_f32_16x16x32_bf16(ar[rt], br[bt], o[rt][bt], 0, 0, 0);
  }

  // ---- epilogue: direct packed stores; block covers full 128B line per c ----
  unsigned short* obase = QKVt + (long)b * NN * CC;
#pragma unroll
  for (int rt = 0; rt < 4; rt++) {
#pragma unroll
    for (int bt = 0; bt < 2; bt++) {
      int c = cw + bt * 16 + r;
      int n = n0 + rt * 16 + g * 4;
      s16x4 pk;
      pk.x = (short)f2bf(o[rt][bt][0]);
      pk.y = (short)f2bf(o[rt][bt][1]);
      pk.z = (short)f2bf(o[rt][bt][2]);
      pk.w = (short)f2bf(o[rt][bt][3]);
      *(s16x4*)(obase + (long)c * NN + n) = pk;
    }
  }
}

extern "C" void kernel_launch(void* const* d_in, const int* in_sizes, int n_in,
                              void* d_out, int out_size, void* d_ws, size_t ws_size,
                              hipStream_t stream) {
  const float* x  = (const float*)d_in[0];
  const float* Wq = (const float*)d_in[1];
  const float* bq = (const float*)d_in[2];
  const float* Wk = (const float*)d_in[3];
  const float* bk = (const float*)d_in[4];
  const float* Wv = (const float*)d_in[5];
  const float* bv = (const float*)d_in[6];
  const float* Wp = (const float*)d_in[7];
  float* out = (float*)d_out;

  const long BNC = (long)BB * NN * CC;

  char* p = (char*)d_ws;
  unsigned short* xb    = (unsigned short*)p; p += BNC * 2;
  unsigned short* wqkvb = (unsigned short*)p; p += 3L * CC * CC * 2;
  float*          bqkv  = (float*)p;          p += 4096;
  unsigned short* Amat  = (unsigned short*)p; p += (long)NN * NN * 2;
  unsigned short* Qb    = (unsigned short*)p; p += BNC * 2;
  unsigned short* Ktb   = (unsigned short*)p; p += BNC * 2;   // tiled Kt
  unsigned short* Vtb   = (unsigned short*)p; p += BNC * 2;   // tiled V5
  unsigned short* QKVt  = (unsigned short*)p; p += BNC * 2;   // [b][c][n]

  // casts + Wp transpose in one launch
  preprocess<<<NCAST + 1024, 256, 0, stream>>>(
      x, Wq, Wk, Wv, bq, bk, bv, Wp, xb, wqkvb, bqkv, Amat);

  // Fused QKV projection: M=1024, N=768, K=256 per batch; 128x128 tiles
  gemm_qkv<<<dim3(BB, 8, 6), 256, 0, stream>>>(xb, wqkvb, bqkv, Qb, Ktb, Vtb);

  // Fused softmax(QK^T)·V -> QKVt[c][n];  64 rows/block, 256 blocks = 1/CU
  attn_fused<<<dim3(BB, NN / 64), 512, 0, stream>>>(Qb, Ktb, Vtb, QKVt);

  // Z[hw][c] = sum_n Amat[hw][n] * QKVt[c][n] : M=1024, N=256, K=1024, f32 out
  gemm_tile<0, 1><<<dim3(BB, 8, 4), 256, 0, stream>>>(
      Amat, NN, 0L, QKVt, NN, (long)NN * CC, nullptr,
      out, CC, (long)NN * CC, NN);
}

// Round 4
// 151.480 us; speedup vs baseline: 1.0299x; 1.0299x over previous
//
#include <hip/hip_runtime.h>
#include <hip/hip_bf16.h>

#define BB 16
#define NN 1024
#define CC 256

typedef __attribute__((ext_vector_type(8))) short bf16x8;
typedef __attribute__((ext_vector_type(4))) short s16x4;
typedef __attribute__((ext_vector_type(4))) float f32x4;

#define GPTR(p) ((const __attribute__((address_space(1))) void*)(p))
#define LPTR(p) ((__attribute__((address_space(3))) void*)(p))

__device__ __forceinline__ unsigned short f2bf(float f) {
  union { float f; unsigned u; } v; v.f = f;
  unsigned r = v.u + 0x7FFFu + ((v.u >> 16) & 1u);
  return (unsigned short)(r >> 16);
}

__device__ __forceinline__ bf16x8 pack8(f32x4 a, f32x4 b) {
  bf16x8 o;
  o[0] = (short)f2bf(a[0]); o[1] = (short)f2bf(a[1]);
  o[2] = (short)f2bf(a[2]); o[3] = (short)f2bf(a[3]);
  o[4] = (short)f2bf(b[0]); o[5] = (short)f2bf(b[1]);
  o[6] = (short)f2bf(b[2]); o[7] = (short)f2bf(b[3]);
  return o;
}

// Tiled GEMM: C[m][n] = sum_k A[m][k]*Bt[n][k]. BM=128 BN=64 BK=64.
// Grid: (batch, m-tiles, n-tiles)  [batch on x => XCD affinity]
template <int BIAS_MODE, int F32OUT>
__global__ __launch_bounds__(256) void gemm_tile(
    const unsigned short* __restrict__ A, int lda, long sA,
    const unsigned short* __restrict__ Bt, int ldb, long sB,
    const float* __restrict__ bias,
    void* __restrict__ Out, int ldo, long sO, int K) {
  __shared__ unsigned short As[2 * 128 * 32];
  __shared__ unsigned short Bs[2 * 64 * 32];
  int b = blockIdx.x;
  int m0 = blockIdx.y * 128;
  int n0 = blockIdx.z * 64;
  int t = threadIdx.x;
  int w = t >> 6, lane = t & 63;
  int wm = (w >> 1) * 64, wn = (w & 1) * 32;
  int r = lane & 15, g = lane >> 4;

  const unsigned short* Ab = A + (long)b * sA;
  const unsigned short* Bb = Bt + (long)b * sB;

  int srow = t >> 2;
  int scol = (t & 3) * 8;

  f32x4 acc[4][2];
#pragma unroll
  for (int i = 0; i < 4; i++)
#pragma unroll
    for (int j = 0; j < 2; j++) acc[i][j] = (f32x4){0.f, 0.f, 0.f, 0.f};

  for (int k0 = 0; k0 < K; k0 += 64) {
    __syncthreads();
#pragma unroll
    for (int kh = 0; kh < 2; kh++) {
#pragma unroll
      for (int jj = 0; jj < 2; jj++) {
        __builtin_amdgcn_global_load_lds(
            GPTR(Ab + (long)(m0 + srow + jj * 64) * lda + k0 + kh * 32 + scol),
            LPTR(&As[kh * 4096 + jj * 2048 + t * 8]), 16, 0, 0);
      }
      __builtin_amdgcn_global_load_lds(
          GPTR(Bb + (long)(n0 + srow) * ldb + k0 + kh * 32 + scol),
          LPTR(&Bs[kh * 2048 + t * 8]), 16, 0, 0);
    }
    __syncthreads();
#pragma unroll
    for (int kh = 0; kh < 2; kh++) {
      bf16x8 af[4], bfr[2];
#pragma unroll
      for (int ti = 0; ti < 4; ti++)
        af[ti] = *(const bf16x8*)&As[kh * 4096 + (wm + ti * 16 + r) * 32 + g * 8];
#pragma unroll
      for (int tj = 0; tj < 2; tj++)
        bfr[tj] = *(const bf16x8*)&Bs[kh * 2048 + (wn + tj * 16 + r) * 32 + g * 8];
#pragma unroll
      for (int ti = 0; ti < 4; ti++)
#pragma unroll
        for (int tj = 0; tj < 2; tj++)
          acc[ti][tj] = __builtin_amdgcn_mfma_f32_16x16x32_bf16(af[ti], bfr[tj], acc[ti][tj], 0, 0, 0);
    }
  }

#pragma unroll
  for (int ti = 0; ti < 4; ti++) {
#pragma unroll
    for (int tj = 0; tj < 2; tj++) {
      int col = n0 + wn + tj * 16 + r;
      float bc = (BIAS_MODE == 1) ? bias[col] : 0.0f;
#pragma unroll
      for (int rr = 0; rr < 4; rr++) {
        int row = m0 + wm + ti * 16 + g * 4 + rr;
        float val = acc[ti][tj][rr] + bc;
        long oidx = (long)b * sO + (long)row * ldo + col;
        if (F32OUT)
          ((float*)Out)[oidx] = val;
        else
          ((unsigned short*)Out)[oidx] = f2bf(val);
      }
    }
  }
}

// Fused QKV projection with INLINE f32->bf16 conversion (preprocess deleted).
// Grid: (batch=16, 8 m-tiles, 7): z<6 = GEMM n-tiles of 128; z==6 = Wp
// transpose (128 blocks x 8 units -> Amat).
// A panel (x) is reg-prefetched one k-step ahead (T14) and converted in
// registers; B panel (Wq/Wk/Wv) is L2-hot after the first blocks, loaded
// in-step. K written TILED: Kt[c>>5][tok][c&31]; V TILED:
// V5[c>>4][m>>3][c&15][m&7].
__global__ __launch_bounds__(256) void gemm_qkv(
    const float* __restrict__ x,
    const float* __restrict__ Wq, const float* __restrict__ Wk,
    const float* __restrict__ Wv,
    const float* __restrict__ bq, const float* __restrict__ bk,
    const float* __restrict__ bv,
    const float* __restrict__ Wp,
    unsigned short* __restrict__ Qb, unsigned short* __restrict__ Kb,
    unsigned short* __restrict__ Vtb, unsigned short* __restrict__ Amat) {
  __shared__ unsigned short As[2 * 128 * 32];  // 16 KB
  __shared__ unsigned short Bs[2 * 128 * 32];  // 16 KB
  __shared__ float tile[32][33];               // transpose path only

  if (blockIdx.z == 6) {
    // ---- Wp transpose: Amat[h*32+w][n] = Wp[h][n][w], bf16 ----
    int id = blockIdx.x * 8 + blockIdx.y;      // 0..127
#pragma unroll 1
    for (int u = 0; u < 8; u++) {
      int wb = id * 8 + u;                     // 0..1023
      int h = wb >> 5;
      int n0w = (wb & 31) * 32;
#pragma unroll
      for (int j = 0; j < 4; j++) {
        int idx = threadIdx.x + j * 256;
        int a = idx >> 5, wc = idx & 31;
        tile[a][wc] = Wp[(size_t)h * (NN * 32) + (size_t)(n0w + a) * 32 + wc];
      }
      __syncthreads();
#pragma unroll
      for (int j = 0; j < 4; j++) {
        int idx = threadIdx.x + j * 256;
        int wc = idx >> 5, a = idx & 31;
        Amat[(size_t)(h * 32 + wc) * NN + n0w + a] = f2bf(tile[a][wc]);
      }
      __syncthreads();
    }
    return;
  }

  int b = blockIdx.x;
  int m0 = blockIdx.y * 128;
  int n0 = blockIdx.z * 128;
  int t = threadIdx.x;
  int w = t >> 6, lane = t & 63;
  int wm = (w >> 1) * 64, wn = (w & 1) * 64;
  int r = lane & 15, g = lane >> 4;

  const float* Ab = x + (long)b * NN * CC;
  int srow = t >> 2;            // 0..63
  int scol = (t & 3) * 8;

  // B row sources: n = n0 + jj*64 + srow; each jj-half stays in one W matrix
  const float* Wsel[2];
  int wrow[2];
#pragma unroll
  for (int jj = 0; jj < 2; jj++) {
    int nbase = n0 + jj * 64;
    int seg = nbase >> 8;
    Wsel[jj] = (seg == 0) ? Wq : (seg == 1 ? Wk : Wv);
    wrow[jj] = (nbase + srow) & 255;
  }

  f32x4 acc[4][4];
#pragma unroll
  for (int i = 0; i < 4; i++)
#pragma unroll
    for (int j = 0; j < 4; j++) acc[i][j] = (f32x4){0.f, 0.f, 0.f, 0.f};

  // A-panel register prefetch (one k-step ahead)
  f32x4 pa[4][2];
#pragma unroll
  for (int kh = 0; kh < 2; kh++)
#pragma unroll
    for (int jj = 0; jj < 2; jj++) {
      const float* src = Ab + (long)(m0 + srow + jj * 64) * CC + kh * 32 + scol;
      pa[kh * 2 + jj][0] = *(const f32x4*)src;
      pa[kh * 2 + jj][1] = *(const f32x4*)(src + 4);
    }

  for (int k0 = 0; k0 < CC; k0 += 64) {
    __syncthreads();   // prev-step LDS reads done
#pragma unroll
    for (int kh = 0; kh < 2; kh++) {
#pragma unroll
      for (int jj = 0; jj < 2; jj++) {
        const float* wsrc = Wsel[jj] + (long)wrow[jj] * CC + k0 + kh * 32 + scol;
        f32x4 b0 = *(const f32x4*)wsrc;
        f32x4 b1 = *(const f32x4*)(wsrc + 4);
        *(bf16x8*)&Bs[kh * 4096 + jj * 2048 + t * 8] = pack8(b0, b1);
        *(bf16x8*)&As[kh * 4096 + jj * 2048 + t * 8] =
            pack8(pa[kh * 2 + jj][0], pa[kh * 2 + jj][1]);
      }
    }
    __syncthreads();   // staged
    if (k0 < CC - 64) {
#pragma unroll
      for (int kh = 0; kh < 2; kh++)
#pragma unroll
        for (int jj = 0; jj < 2; jj++) {
          const float* src =
              Ab + (long)(m0 + srow + jj * 64) * CC + k0 + 64 + kh * 32 + scol;
          pa[kh * 2 + jj][0] = *(const f32x4*)src;
          pa[kh * 2 + jj][1] = *(const f32x4*)(src + 4);
        }
    }
#pragma unroll
    for (int kh = 0; kh < 2; kh++) {
      bf16x8 af[4], bfr[4];
#pragma unroll
      for (int ti = 0; ti < 4; ti++)
        af[ti] = *(const bf16x8*)&As[kh * 4096 + (wm + ti * 16 + r) * 32 + g * 8];
#pragma unroll
      for (int tj = 0; tj < 4; tj++)
        bfr[tj] = *(const bf16x8*)&Bs[kh * 4096 + (wn + tj * 16 + r) * 32 + g * 8];
#pragma unroll
      for (int ti = 0; ti < 4; ti++)
#pragma unroll
        for (int tj = 0; tj < 4; tj++)
          acc[ti][tj] = __builtin_amdgcn_mfma_f32_16x16x32_bf16(af[ti], bfr[tj], acc[ti][tj], 0, 0, 0);
    }
  }

  int sege = (n0 + wn) >> 8;
  const float* bsel = (sege == 0) ? bq : (sege == 1 ? bk : bv);
  int seg = n0 >> 8;   // 128-col span stays within one 256-col segment
#pragma unroll
  for (int ti = 0; ti < 4; ti++) {
#pragma unroll
    for (int tj = 0; tj < 4; tj++) {
      int col = n0 + wn + tj * 16 + r;
      int c = col & 255;
      float bc = bsel[c];
#pragma unroll
      for (int rr = 0; rr < 4; rr++) {
        int row = m0 + wm + ti * 16 + g * 4 + rr;   // token index
        float val = acc[ti][tj][rr] + bc;
        long base = (long)b * NN * CC;
        if (seg == 0) {
          Qb[base + (long)row * CC + c] = f2bf(val);
        } else if (seg == 1) {
          Kb[base + ((long)(c >> 5) * NN + row) * 32 + (c & 31)] = f2bf(val);
        } else {
          Vtb[base + ((((long)(c >> 4) * 128 + (row >> 3)) * 16 + (c & 15)) * 8 + (row & 7))] = f2bf(val);
        }
      }
    }
  }
}

// Fused scores+softmax+PV v12. 512 thr = 8 waves; 64 Q-rows/block.
// Grid (batch, 16) = 256 blocks = 1/CU; all blocks of batch b land on
// XCD b%8 -> K/V L2-resident, re-read 16x.
// Phase 1 (QK^T): barrier-free per-wave double-buffered DMA with counted
//   vmcnt(8); s_setprio(1) around MFMA cluster (T5).
// Phase 3: O = P V with explicit 1-deep V register pipeline; first V frags
//   issued BEFORE softmax so their latency hides under softmax VALU.
__global__ __launch_bounds__(512, 2) void attn_fused(
    const unsigned short* __restrict__ Q,    // [B][1024][256]
    const unsigned short* __restrict__ Kt,   // [B][8][1024][32] tiled
    const unsigned short* __restrict__ Vt,   // [B] tiled V5
    unsigned short* __restrict__ QKVt) {     // [B][256][1024]
  __shared__ unsigned short ShBuf[64 * 1024];  // 128 KB: 2x64KB K slabs, then P[64][1024]
  __shared__ float red[8][64];
  int b = blockIdx.x;
  int n0 = blockIdx.y * 64;
  int t = threadIdx.x;
  int w = t >> 6, lane = t & 63;
  int r = lane & 15, g = lane >> 4;

  // wave-private K slice: tokens [w*128, +128), 32 ch per slab, 8 KB
  const unsigned short* kslab = Kt + (long)b * NN * CC + w * 128 * 32;
  unsigned short* wbuf0 = &ShBuf[w * 4096];           // 8 KB slice in buffer 0
  unsigned short* wbuf1 = &ShBuf[32768 + w * 4096];   // 8 KB slice in buffer 1

  const unsigned short* qbase = Q + ((long)b * NN + n0 + r) * CC + g * 8;

  // prologue: stage slab 0 (own slice), load q-frags slab 0
#pragma unroll
  for (int j = 0; j < 8; j++)
    __builtin_amdgcn_global_load_lds(GPTR(kslab + j * 512 + lane * 8),
                                     LPTR(wbuf0 + j * 512 + lane * 8), 16, 0, 0);
  bf16x8 qa[4];
#pragma unroll
  for (int rt = 0; rt < 4; rt++)
    qa[rt] = *(const bf16x8*)(qbase + rt * 16 * CC);

  f32x4 acc[4][8];
#pragma unroll
  for (int i = 0; i < 4; i++)
#pragma unroll
    for (int j = 0; j < 8; j++) acc[i][j] = (f32x4){0.f, 0.f, 0.f, 0.f};

#pragma unroll
  for (int kk = 0; kk < 8; kk++) {
    unsigned short* cur = (kk & 1) ? wbuf1 : wbuf0;
    unsigned short* nxt = (kk & 1) ? wbuf0 : wbuf1;
    if (kk < 7) {
      const unsigned short* src = kslab + (long)(kk + 1) * (NN * 32);
#pragma unroll
      for (int j = 0; j < 8; j++)
        __builtin_amdgcn_global_load_lds(GPTR(src + j * 512 + lane * 8),
                                         LPTR(nxt + j * 512 + lane * 8), 16, 0, 0);
      asm volatile("s_waitcnt vmcnt(8)" ::: "memory");  // slab kk landed; kk+1 in flight
    } else {
      asm volatile("s_waitcnt vmcnt(0)" ::: "memory");
    }
    __builtin_amdgcn_sched_barrier(0);
    bf16x8 qn[4];
    if (kk < 7) {
#pragma unroll
      for (int rt = 0; rt < 4; rt++)
        qn[rt] = *(const bf16x8*)(qbase + (kk + 1) * 32 + rt * 16 * CC);
    }
    __builtin_amdgcn_s_setprio(1);
#pragma unroll
    for (int ct = 0; ct < 8; ct++) {
      bf16x8 kf = *(const bf16x8*)&cur[(ct * 16 + r) * 32 + g * 8];
#pragma unroll
      for (int rt = 0; rt < 4; rt++)
        acc[rt][ct] = __builtin_amdgcn_mfma_f32_16x16x32_bf16(qa[rt], kf, acc[rt][ct], 0, 0, 0);
    }
    __builtin_amdgcn_s_setprio(0);
    if (kk < 7) {
#pragma unroll
      for (int rt = 0; rt < 4; rt++) qa[rt] = qn[rt];
    }
    __builtin_amdgcn_sched_barrier(0);  // pin cross-iteration order (stage vs prior reads)
  }

  // prefetch first V fragments (phase 3, m0=0) — latency hides under softmax
  const unsigned short* vbase = Vt + (long)b * NN * CC;  // tiled V5
  int cw = w * 32;
  bf16x8 brp[2];
#pragma unroll
  for (int bt = 0; bt < 2; bt++) {
    long vidx = (((long)((cw >> 4) + bt) * 128 + g) * 16 + r) * 8;
    brp[bt] = *(const bf16x8*)(vbase + vidx);
  }
  __builtin_amdgcn_sched_barrier(0);

  // ---- softmax ----  acc[rt][ct][rr]: row = rt*16+g*4+rr, col = w*128+ct*16+r
  float mrow[4][4];
#pragma unroll
  for (int rt = 0; rt < 4; rt++) {
#pragma unroll
    for (int rr = 0; rr < 4; rr++) {
      float m = acc[rt][0][rr];
#pragma unroll
      for (int ct = 1; ct < 8; ct++) m = fmaxf(m, acc[rt][ct][rr]);
#pragma unroll
      for (int d = 1; d < 16; d <<= 1) m = fmaxf(m, __shfl_xor(m, d, 64));
      mrow[rt][rr] = m;
    }
  }
  if (r == 0) {
#pragma unroll
    for (int rt = 0; rt < 4; rt++)
#pragma unroll
      for (int rr = 0; rr < 4; rr++)
        red[w][rt * 16 + g * 4 + rr] = mrow[rt][rr];
  }
  __syncthreads();   // #1: also orders all phase-1 K reads before P writes below
#pragma unroll
  for (int rt = 0; rt < 4; rt++) {
#pragma unroll
    for (int rr = 0; rr < 4; rr++) {
      int row = rt * 16 + g * 4 + rr;
      float m = red[0][row];
#pragma unroll
      for (int w2 = 1; w2 < 8; w2++) m = fmaxf(m, red[w2][row]);
      mrow[rt][rr] = m;
    }
  }
  __syncthreads();   // #2: WAR before sum overwrites red
  float ssum[4][4];
#pragma unroll
  for (int rt = 0; rt < 4; rt++) {
#pragma unroll
    for (int rr = 0; rr < 4; rr++) {
      float s = 0.f;
#pragma unroll
      for (int ct = 0; ct < 8; ct++) {
        float e = exp2f((acc[rt][ct][rr] - mrow[rt][rr]) * 1.44269504088896f);
        acc[rt][ct][rr] = e;
        s += e;
      }
#pragma unroll
      for (int d = 1; d < 16; d <<= 1) s += __shfl_xor(s, d, 64);
      ssum[rt][rr] = s;
    }
  }
  if (r == 0) {
#pragma unroll
    for (int rt = 0; rt < 4; rt++)
#pragma unroll
      for (int rr = 0; rr < 4; rr++)
        red[w][rt * 16 + g * 4 + rr] = ssum[rt][rr];
  }
  __syncthreads();   // #3
  // ---- phase 2: P -> LDS (overlays K buffers), chunk-XOR swizzle (prow&7) ----
#pragma unroll
  for (int rt = 0; rt < 4; rt++) {
#pragma unroll
    for (int rr = 0; rr < 4; rr++) {
      int prow = rt * 16 + g * 4 + rr;
      float s = 0.f;
#pragma unroll
      for (int w2 = 0; w2 < 8; w2++) s += red[w2][prow];
      float inv = 1.0f / s;
      int sw = prow & 7;
#pragma unroll
      for (int ct = 0; ct < 8; ct++) {
        int col = w * 128 + ct * 16 + r;
        int chunk = (col >> 3) ^ sw;
        ShBuf[prow * 1024 + chunk * 8 + (col & 7)] = f2bf(acc[rt][ct][rr] * inv);
      }
    }
  }
  __syncthreads();   // #4

  // ---- phase 3: O = P V.  Wave w owns O cols [w*32,+32), rows n0..n0+64.
  f32x4 o[4][2];
#pragma unroll
  for (int i = 0; i < 4; i++)
#pragma unroll
    for (int j = 0; j < 2; j++) o[i][j] = (f32x4){0.f, 0.f, 0.f, 0.f};

#pragma unroll 4
  for (int m0 = 0; m0 < NN; m0 += 32) {
    bf16x8 ar[4], br[2];
    br[0] = brp[0]; br[1] = brp[1];
    if (m0 + 32 < NN) {
#pragma unroll
      for (int bt = 0; bt < 2; bt++) {
        long vidx = (((long)((cw >> 4) + bt) * 128 + ((m0 + 32) >> 3) + g) * 16 + r) * 8;
        brp[bt] = *(const bf16x8*)(vbase + vidx);
      }
    }
#pragma unroll
    for (int rt = 0; rt < 4; rt++) {
      int prow = rt * 16 + r;
      int chunk = ((m0 >> 3) + g) ^ (prow & 7);
      ar[rt] = *(const bf16x8*)&ShBuf[prow * 1024 + chunk * 8];
    }
    __builtin_amdgcn_s_setprio(1);
#pragma unroll
    for (int rt = 0; rt < 4; rt++)
#pragma unroll
      for (int bt = 0; bt < 2; bt++)
        o[rt][bt] = __builtin_amdgcn_mfma_f32_16x16x32_bf16(ar[rt], br[bt], o[rt][bt], 0, 0, 0);
    __builtin_amdgcn_s_setprio(0);
  }

  // ---- epilogue: direct packed stores; block covers full 128B line per c ----
  unsigned short* obase = QKVt + (long)b * NN * CC;
#pragma unroll
  for (int rt = 0; rt < 4; rt++) {
#pragma unroll
    for (int bt = 0; bt < 2; bt++) {
      int c = cw + bt * 16 + r;
      int n = n0 + rt * 16 + g * 4;
      s16x4 pk;
      pk.x = (short)f2bf(o[rt][bt][0]);
      pk.y = (short)f2bf(o[rt][bt][1]);
      pk.z = (short)f2bf(o[rt][bt][2]);
      pk.w = (short)f2bf(o[rt][bt][3]);
      *(s16x4*)(obase + (long)c * NN + n) = pk;
    }
  }
}

extern "C" void kernel_launch(void* const* d_in, const int* in_sizes, int n_in,
                              void* d_out, int out_size, void* d_ws, size_t ws_size,
                              hipStream_t stream) {
  const float* x  = (const float*)d_in[0];
  const float* Wq = (const float*)d_in[1];
  const float* bq = (const float*)d_in[2];
  const float* Wk = (const float*)d_in[3];
  const float* bk = (const float*)d_in[4];
  const float* Wv = (const float*)d_in[5];
  const float* bv = (const float*)d_in[6];
  const float* Wp = (const float*)d_in[7];
  float* out = (float*)d_out;

  const long BNC = (long)BB * NN * CC;

  char* p = (char*)d_ws;
  unsigned short* Amat  = (unsigned short*)p; p += (long)NN * NN * 2;
  unsigned short* Qb    = (unsigned short*)p; p += BNC * 2;
  unsigned short* Ktb   = (unsigned short*)p; p += BNC * 2;   // tiled Kt
  unsigned short* Vtb   = (unsigned short*)p; p += BNC * 2;   // tiled V5
  unsigned short* QKVt  = (unsigned short*)p; p += BNC * 2;   // [b][c][n]

  // Fused QKV projection (inline f32->bf16) + Wp transpose (z==6 slice)
  gemm_qkv<<<dim3(BB, 8, 7), 256, 0, stream>>>(
      x, Wq, Wk, Wv, bq, bk, bv, Wp, Qb, Ktb, Vtb, Amat);

  // Fused softmax(QK^T)·V -> QKVt[c][n];  64 rows/block, 256 blocks = 1/CU
  attn_fused<<<dim3(BB, NN / 64), 512, 0, stream>>>(Qb, Ktb, Vtb, QKVt);

  // Z[hw][c] = sum_n Amat[hw][n] * QKVt[c][n] : M=1024, N=256, K=1024, f32 out
  gemm_tile<0, 1><<<dim3(BB, 8, 4), 256, 0, stream>>>(
      Amat, NN, 0L, QKVt, NN, (long)NN * CC, nullptr,
      out, CC, (long)NN * CC, NN);
}

// Round 5
// 149.940 us; speedup vs baseline: 1.0404x; 1.0103x over previous
//
#include <hip/hip_runtime.h>
#include <hip/hip_bf16.h>

#define BB 16
#define NN 1024
#define CC 256

typedef __attribute__((ext_vector_type(8))) short bf16x8;
typedef __attribute__((ext_vector_type(4))) short s16x4;
typedef __attribute__((ext_vector_type(4))) float f32x4;

#define GPTR(p) ((const __attribute__((address_space(1))) void*)(p))
#define LPTR(p) ((__attribute__((address_space(3))) void*)(p))

__device__ __forceinline__ unsigned short f2bf(float f) {
  union { float f; unsigned u; } v; v.f = f;
  unsigned r = v.u + 0x7FFFu + ((v.u >> 16) & 1u);
  return (unsigned short)(r >> 16);
}

__device__ __forceinline__ bf16x8 pack8(f32x4 a, f32x4 b) {
  bf16x8 o;
  o[0] = (short)f2bf(a[0]); o[1] = (short)f2bf(a[1]);
  o[2] = (short)f2bf(a[2]); o[3] = (short)f2bf(a[3]);
  o[4] = (short)f2bf(b[0]); o[5] = (short)f2bf(b[1]);
  o[6] = (short)f2bf(b[2]); o[7] = (short)f2bf(b[3]);
  return o;
}

// Tiled GEMM: C[m][n] = sum_k A[m][k]*Bt[n][k]. BM=128 BN=64 BK=64.
// v2: double-buffered LDS + counted vmcnt + raw barriers (T3-minimum).
// Per K-step: issue next tile's 6 DMA loads; s_waitcnt vmcnt(6) (current
// landed, next in flight); s_barrier; compute; s_barrier (buffer WAR).
// No full vmcnt(0) drains in the main loop (the old __syncthreads drained
// every step, exposing the full DMA round-trip 16x per block).
// Grid: (batch, m-tiles, n-tiles)  [batch on x => XCD affinity]
template <int BIAS_MODE, int F32OUT>
__global__ __launch_bounds__(256) void gemm_tile(
    const unsigned short* __restrict__ A, int lda, long sA,
    const unsigned short* __restrict__ Bt, int ldb, long sB,
    const float* __restrict__ bias,
    void* __restrict__ Out, int ldo, long sO, int K) {
  __shared__ unsigned short As[2][2 * 128 * 32];   // 2 x 16 KB
  __shared__ unsigned short Bs[2][2 * 64 * 32];    // 2 x 8 KB
  int b = blockIdx.x;
  int m0 = blockIdx.y * 128;
  int n0 = blockIdx.z * 64;
  int t = threadIdx.x;
  int w = t >> 6, lane = t & 63;
  int wm = (w >> 1) * 64, wn = (w & 1) * 32;
  int r = lane & 15, g = lane >> 4;

  const unsigned short* Ab = A + (long)b * sA;
  const unsigned short* Bb = Bt + (long)b * sB;

  int srow = t >> 2;
  int scol = (t & 3) * 8;

  f32x4 acc[4][2];
#pragma unroll
  for (int i = 0; i < 4; i++)
#pragma unroll
    for (int j = 0; j < 2; j++) acc[i][j] = (f32x4){0.f, 0.f, 0.f, 0.f};

#define STAGE_GT(buf, k0)                                                     \
  do {                                                                        \
    _Pragma("unroll") for (int kh = 0; kh < 2; kh++) {                        \
      _Pragma("unroll") for (int jj = 0; jj < 2; jj++) {                      \
        __builtin_amdgcn_global_load_lds(                                     \
            GPTR(Ab + (long)(m0 + srow + jj * 64) * lda + (k0) + kh * 32 +    \
                 scol),                                                       \
            LPTR(&As[buf][kh * 4096 + jj * 2048 + t * 8]), 16, 0, 0);         \
      }                                                                       \
      __builtin_amdgcn_global_load_lds(                                       \
          GPTR(Bb + (long)(n0 + srow) * ldb + (k0) + kh * 32 + scol),         \
          LPTR(&Bs[buf][kh * 2048 + t * 8]), 16, 0, 0);                       \
    }                                                                         \
  } while (0)

  int nt = K >> 6;
  STAGE_GT(0, 0);
  for (int tt = 0; tt < nt; ++tt) {
    int cb = tt & 1;
    if (tt < nt - 1) {
      STAGE_GT(cb ^ 1, (tt + 1) * 64);
      asm volatile("s_waitcnt vmcnt(6)" ::: "memory");
    } else {
      asm volatile("s_waitcnt vmcnt(0)" ::: "memory");
    }
    __builtin_amdgcn_sched_barrier(0);
    __builtin_amdgcn_s_barrier();          // all waves' current-buf DMA landed
    __builtin_amdgcn_sched_barrier(0);
#pragma unroll
    for (int kh = 0; kh < 2; kh++) {
      bf16x8 af[4], bfr[2];
#pragma unroll
      for (int ti = 0; ti < 4; ti++)
        af[ti] = *(const bf16x8*)&As[cb][kh * 4096 + (wm + ti * 16 + r) * 32 + g * 8];
#pragma unroll
      for (int tj = 0; tj < 2; tj++)
        bfr[tj] = *(const bf16x8*)&Bs[cb][kh * 2048 + (wn + tj * 16 + r) * 32 + g * 8];
#pragma unroll
      for (int ti = 0; ti < 4; ti++)
#pragma unroll
        for (int tj = 0; tj < 2; tj++)
          acc[ti][tj] = __builtin_amdgcn_mfma_f32_16x16x32_bf16(af[ti], bfr[tj], acc[ti][tj], 0, 0, 0);
    }
    __builtin_amdgcn_s_barrier();          // reads done before next overwrite
  }
#undef STAGE_GT

#pragma unroll
  for (int ti = 0; ti < 4; ti++) {
#pragma unroll
    for (int tj = 0; tj < 2; tj++) {
      int col = n0 + wn + tj * 16 + r;
      float bc = (BIAS_MODE == 1) ? bias[col] : 0.0f;
#pragma unroll
      for (int rr = 0; rr < 4; rr++) {
        int row = m0 + wm + ti * 16 + g * 4 + rr;
        float val = acc[ti][tj][rr] + bc;
        long oidx = (long)b * sO + (long)row * ldo + col;
        if (F32OUT)
          ((float*)Out)[oidx] = val;
        else
          ((unsigned short*)Out)[oidx] = f2bf(val);
      }
    }
  }
}

// Fused QKV projection with INLINE f32->bf16 conversion.
// v2: raw barriers; A AND W reg-prefetched one k-step ahead; the prefetch
// loads stay in flight across both barriers (old __syncthreads drained
// vmcnt(0) at every step, nullifying T14).
// Grid: (batch=16, 8 m-tiles, 7): z<6 = GEMM n-tiles of 128; z==6 = Wp
// transpose (128 blocks x 8 units -> Amat).
// K written TILED: Kt[c>>5][tok][c&31]; V TILED: V5[c>>4][m>>3][c&15][m&7].
__global__ __launch_bounds__(256) void gemm_qkv(
    const float* __restrict__ x,
    const float* __restrict__ Wq, const float* __restrict__ Wk,
    const float* __restrict__ Wv,
    const float* __restrict__ bq, const float* __restrict__ bk,
    const float* __restrict__ bv,
    const float* __restrict__ Wp,
    unsigned short* __restrict__ Qb, unsigned short* __restrict__ Kb,
    unsigned short* __restrict__ Vtb, unsigned short* __restrict__ Amat) {
  __shared__ unsigned short As[2 * 128 * 32];  // 16 KB
  __shared__ unsigned short Bs[2 * 128 * 32];  // 16 KB
  __shared__ float tile[32][33];               // transpose path only

  if (blockIdx.z == 6) {
    // ---- Wp transpose: Amat[h*32+w][n] = Wp[h][n][w], bf16 ----
    int id = blockIdx.x * 8 + blockIdx.y;      // 0..127
#pragma unroll 1
    for (int u = 0; u < 8; u++) {
      int wb = id * 8 + u;                     // 0..1023
      int h = wb >> 5;
      int n0w = (wb & 31) * 32;
#pragma unroll
      for (int j = 0; j < 4; j++) {
        int idx = threadIdx.x + j * 256;
        int a = idx >> 5, wc = idx & 31;
        tile[a][wc] = Wp[(size_t)h * (NN * 32) + (size_t)(n0w + a) * 32 + wc];
      }
      __syncthreads();
#pragma unroll
      for (int j = 0; j < 4; j++) {
        int idx = threadIdx.x + j * 256;
        int wc = idx >> 5, a = idx & 31;
        Amat[(size_t)(h * 32 + wc) * NN + n0w + a] = f2bf(tile[a][wc]);
      }
      __syncthreads();
    }
    return;
  }

  int b = blockIdx.x;
  int m0 = blockIdx.y * 128;
  int n0 = blockIdx.z * 128;
  int t = threadIdx.x;
  int w = t >> 6, lane = t & 63;
  int wm = (w >> 1) * 64, wn = (w & 1) * 64;
  int r = lane & 15, g = lane >> 4;

  const float* Ab = x + (long)b * NN * CC;
  int srow = t >> 2;            // 0..63
  int scol = (t & 3) * 8;

  // B row sources: n = n0 + jj*64 + srow; each jj-half stays in one W matrix
  const float* Wsel[2];
  int wrow[2];
#pragma unroll
  for (int jj = 0; jj < 2; jj++) {
    int nbase = n0 + jj * 64;
    int seg = nbase >> 8;
    Wsel[jj] = (seg == 0) ? Wq : (seg == 1 ? Wk : Wv);
    wrow[jj] = (nbase + srow) & 255;
  }

  f32x4 acc[4][4];
#pragma unroll
  for (int i = 0; i < 4; i++)
#pragma unroll
    for (int j = 0; j < 4; j++) acc[i][j] = (f32x4){0.f, 0.f, 0.f, 0.f};

  // register prefetch, one k-step ahead: A panel and W panel
  f32x4 pa[4][2], pw[4][2];
#pragma unroll
  for (int kh = 0; kh < 2; kh++)
#pragma unroll
    for (int jj = 0; jj < 2; jj++) {
      const float* asrc = Ab + (long)(m0 + srow + jj * 64) * CC + kh * 32 + scol;
      pa[kh * 2 + jj][0] = *(const f32x4*)asrc;
      pa[kh * 2 + jj][1] = *(const f32x4*)(asrc + 4);
      const float* wsrc = Wsel[jj] + (long)wrow[jj] * CC + kh * 32 + scol;
      pw[kh * 2 + jj][0] = *(const f32x4*)wsrc;
      pw[kh * 2 + jj][1] = *(const f32x4*)(wsrc + 4);
    }

  for (int k0 = 0; k0 < CC; k0 += 64) {
    if (k0) __builtin_amdgcn_s_barrier();   // prev compute's LDS reads done
    // pack current step into LDS (reads pa/pw loaded last step)
#pragma unroll
    for (int kh = 0; kh < 2; kh++)
#pragma unroll
      for (int jj = 0; jj < 2; jj++) {
        *(bf16x8*)&As[kh * 4096 + jj * 2048 + t * 8] =
            pack8(pa[kh * 2 + jj][0], pa[kh * 2 + jj][1]);
        *(bf16x8*)&Bs[kh * 4096 + jj * 2048 + t * 8] =
            pack8(pw[kh * 2 + jj][0], pw[kh * 2 + jj][1]);
      }
    // issue next step's loads; they stay in flight across both barriers
    if (k0 < CC - 64) {
#pragma unroll
      for (int kh = 0; kh < 2; kh++)
#pragma unroll
        for (int jj = 0; jj < 2; jj++) {
          const float* asrc =
              Ab + (long)(m0 + srow + jj * 64) * CC + k0 + 64 + kh * 32 + scol;
          pa[kh * 2 + jj][0] = *(const f32x4*)asrc;
          pa[kh * 2 + jj][1] = *(const f32x4*)(asrc + 4);
          const float* wsrc =
              Wsel[jj] + (long)wrow[jj] * CC + k0 + 64 + kh * 32 + scol;
          pw[kh * 2 + jj][0] = *(const f32x4*)wsrc;
          pw[kh * 2 + jj][1] = *(const f32x4*)(wsrc + 4);
        }
    }
    asm volatile("s_waitcnt lgkmcnt(0)" ::: "memory");  // ds_writes visible
    __builtin_amdgcn_sched_barrier(0);
    __builtin_amdgcn_s_barrier();
    __builtin_amdgcn_sched_barrier(0);
#pragma unroll
    for (int kh = 0; kh < 2; kh++) {
      bf16x8 af[4], bfr[4];
#pragma unroll
      for (int ti = 0; ti < 4; ti++)
        af[ti] = *(const bf16x8*)&As[kh * 4096 + (wm + ti * 16 + r) * 32 + g * 8];
#pragma unroll
      for (int tj = 0; tj < 4; tj++)
        bfr[tj] = *(const bf16x8*)&Bs[kh * 4096 + (wn + tj * 16 + r) * 32 + g * 8];
#pragma unroll
      for (int ti = 0; ti < 4; ti++)
#pragma unroll
        for (int tj = 0; tj < 4; tj++)
          acc[ti][tj] = __builtin_amdgcn_mfma_f32_16x16x32_bf16(af[ti], bfr[tj], acc[ti][tj], 0, 0, 0);
    }
  }

  int sege = (n0 + wn) >> 8;
  const float* bsel = (sege == 0) ? bq : (sege == 1 ? bk : bv);
  int seg = n0 >> 8;   // 128-col span stays within one 256-col segment
#pragma unroll
  for (int ti = 0; ti < 4; ti++) {
#pragma unroll
    for (int tj = 0; tj < 4; tj++) {
      int col = n0 + wn + tj * 16 + r;
      int c = col & 255;
      float bc = bsel[c];
#pragma unroll
      for (int rr = 0; rr < 4; rr++) {
        int row = m0 + wm + ti * 16 + g * 4 + rr;   // token index
        float val = acc[ti][tj][rr] + bc;
        long base = (long)b * NN * CC;
        if (seg == 0) {
          Qb[base + (long)row * CC + c] = f2bf(val);
        } else if (seg == 1) {
          Kb[base + ((long)(c >> 5) * NN + row) * 32 + (c & 31)] = f2bf(val);
        } else {
          Vtb[base + ((((long)(c >> 4) * 128 + (row >> 3)) * 16 + (c & 15)) * 8 + (row & 7))] = f2bf(val);
        }
      }
    }
  }
}

// Fused scores+softmax+PV v12. 512 thr = 8 waves; 64 Q-rows/block.
// Grid (batch, 16) = 256 blocks = 1/CU; all blocks of batch b land on
// XCD b%8 -> K/V L2-resident, re-read 16x.
// Phase 1 (QK^T): barrier-free per-wave double-buffered DMA with counted
//   vmcnt(8); s_setprio(1) around MFMA cluster (T5).
// Phase 3: O = P V with explicit 1-deep V register pipeline; first V frags
//   issued BEFORE softmax so their latency hides under softmax VALU.
__global__ __launch_bounds__(512, 2) void attn_fused(
    const unsigned short* __restrict__ Q,    // [B][1024][256]
    const unsigned short* __restrict__ Kt,   // [B][8][1024][32] tiled
    const unsigned short* __restrict__ Vt,   // [B] tiled V5
    unsigned short* __restrict__ QKVt) {     // [B][256][1024]
  __shared__ unsigned short ShBuf[64 * 1024];  // 128 KB: 2x64KB K slabs, then P[64][1024]
  __shared__ float red[8][64];
  int b = blockIdx.x;
  int n0 = blockIdx.y * 64;
  int t = threadIdx.x;
  int w = t >> 6, lane = t & 63;
  int r = lane & 15, g = lane >> 4;

  // wave-private K slice: tokens [w*128, +128), 32 ch per slab, 8 KB
  const unsigned short* kslab = Kt + (long)b * NN * CC + w * 128 * 32;
  unsigned short* wbuf0 = &ShBuf[w * 4096];           // 8 KB slice in buffer 0
  unsigned short* wbuf1 = &ShBuf[32768 + w * 4096];   // 8 KB slice in buffer 1

  const unsigned short* qbase = Q + ((long)b * NN + n0 + r) * CC + g * 8;

  // prologue: stage slab 0 (own slice), load q-frags slab 0
#pragma unroll
  for (int j = 0; j < 8; j++)
    __builtin_amdgcn_global_load_lds(GPTR(kslab + j * 512 + lane * 8),
                                     LPTR(wbuf0 + j * 512 + lane * 8), 16, 0, 0);
  bf16x8 qa[4];
#pragma unroll
  for (int rt = 0; rt < 4; rt++)
    qa[rt] = *(const bf16x8*)(qbase + rt * 16 * CC);

  f32x4 acc[4][8];
#pragma unroll
  for (int i = 0; i < 4; i++)
#pragma unroll
    for (int j = 0; j < 8; j++) acc[i][j] = (f32x4){0.f, 0.f, 0.f, 0.f};

#pragma unroll
  for (int kk = 0; kk < 8; kk++) {
    unsigned short* cur = (kk & 1) ? wbuf1 : wbuf0;
    unsigned short* nxt = (kk & 1) ? wbuf0 : wbuf1;
    if (kk < 7) {
      const unsigned short* src = kslab + (long)(kk + 1) * (NN * 32);
#pragma unroll
      for (int j = 0; j < 8; j++)
        __builtin_amdgcn_global_load_lds(GPTR(src + j * 512 + lane * 8),
                                         LPTR(nxt + j * 512 + lane * 8), 16, 0, 0);
      asm volatile("s_waitcnt vmcnt(8)" ::: "memory");  // slab kk landed; kk+1 in flight
    } else {
      asm volatile("s_waitcnt vmcnt(0)" ::: "memory");
    }
    __builtin_amdgcn_sched_barrier(0);
    bf16x8 qn[4];
    if (kk < 7) {
#pragma unroll
      for (int rt = 0; rt < 4; rt++)
        qn[rt] = *(const bf16x8*)(qbase + (kk + 1) * 32 + rt * 16 * CC);
    }
    __builtin_amdgcn_s_setprio(1);
#pragma unroll
    for (int ct = 0; ct < 8; ct++) {
      bf16x8 kf = *(const bf16x8*)&cur[(ct * 16 + r) * 32 + g * 8];
#pragma unroll
      for (int rt = 0; rt < 4; rt++)
        acc[rt][ct] = __builtin_amdgcn_mfma_f32_16x16x32_bf16(qa[rt], kf, acc[rt][ct], 0, 0, 0);
    }
    __builtin_amdgcn_s_setprio(0);
    if (kk < 7) {
#pragma unroll
      for (int rt = 0; rt < 4; rt++) qa[rt] = qn[rt];
    }
    __builtin_amdgcn_sched_barrier(0);  // pin cross-iteration order (stage vs prior reads)
  }

  // prefetch first V fragments (phase 3, m0=0) — latency hides under softmax
  const unsigned short* vbase = Vt + (long)b * NN * CC;  // tiled V5
  int cw = w * 32;
  bf16x8 brp[2];
#pragma unroll
  for (int bt = 0; bt < 2; bt++) {
    long vidx = (((long)((cw >> 4) + bt) * 128 + g) * 16 + r) * 8;
    brp[bt] = *(const bf16x8*)(vbase + vidx);
  }
  __builtin_amdgcn_sched_barrier(0);

  // ---- softmax ----  acc[rt][ct][rr]: row = rt*16+g*4+rr, col = w*128+ct*16+r
  float mrow[4][4];
#pragma unroll
  for (int rt = 0; rt < 4; rt++) {
#pragma unroll
    for (int rr = 0; rr < 4; rr++) {
      float m = acc[rt][0][rr];
#pragma unroll
      for (int ct = 1; ct < 8; ct++) m = fmaxf(m, acc[rt][ct][rr]);
#pragma unroll
      for (int d = 1; d < 16; d <<= 1) m = fmaxf(m, __shfl_xor(m, d, 64));
      mrow[rt][rr] = m;
    }
  }
  if (r == 0) {
#pragma unroll
    for (int rt = 0; rt < 4; rt++)
#pragma unroll
      for (int rr = 0; rr < 4; rr++)
        red[w][rt * 16 + g * 4 + rr] = mrow[rt][rr];
  }
  __syncthreads();   // #1: also orders all phase-1 K reads before P writes below
#pragma unroll
  for (int rt = 0; rt < 4; rt++) {
#pragma unroll
    for (int rr = 0; rr < 4; rr++) {
      int row = rt * 16 + g * 4 + rr;
      float m = red[0][row];
#pragma unroll
      for (int w2 = 1; w2 < 8; w2++) m = fmaxf(m, red[w2][row]);
      mrow[rt][rr] = m;
    }
  }
  __syncthreads();   // #2: WAR before sum overwrites red
  float ssum[4][4];
#pragma unroll
  for (int rt = 0; rt < 4; rt++) {
#pragma unroll
    for (int rr = 0; rr < 4; rr++) {
      float s = 0.f;
#pragma unroll
      for (int ct = 0; ct < 8; ct++) {
        float e = exp2f((acc[rt][ct][rr] - mrow[rt][rr]) * 1.44269504088896f);
        acc[rt][ct][rr] = e;
        s += e;
      }
#pragma unroll
      for (int d = 1; d < 16; d <<= 1) s += __shfl_xor(s, d, 64);
      ssum[rt][rr] = s;
    }
  }
  if (r == 0) {
#pragma unroll
    for (int rt = 0; rt < 4; rt++)
#pragma unroll
      for (int rr = 0; rr < 4; rr++)
        red[w][rt * 16 + g * 4 + rr] = ssum[rt][rr];
  }
  __syncthreads();   // #3
  // ---- phase 2: P -> LDS (overlays K buffers), chunk-XOR swizzle (prow&7) ----
#pragma unroll
  for (int rt = 0; rt < 4; rt++) {
#pragma unroll
    for (int rr = 0; rr < 4; rr++) {
      int prow = rt * 16 + g * 4 + rr;
      float s = 0.f;
#pragma unroll
      for (int w2 = 0; w2 < 8; w2++) s += red[w2][prow];
      float inv = 1.0f / s;
      int sw = prow & 7;
#pragma unroll
      for (int ct = 0; ct < 8; ct++) {
        int col = w * 128 + ct * 16 + r;
        int chunk = (col >> 3) ^ sw;
        ShBuf[prow * 1024 + chunk * 8 + (col & 7)] = f2bf(acc[rt][ct][rr] * inv);
      }
    }
  }
  __syncthreads();   // #4

  // ---- phase 3: O = P V.  Wave w owns O cols [w*32,+32), rows n0..n0+64.
  f32x4 o[4][2];
#pragma unroll
  for (int i = 0; i < 4; i++)
#pragma unroll
    for (int j = 0; j < 2; j++) o[i][j] = (f32x4){0.f, 0.f, 0.f, 0.f};

#pragma unroll 4
  for (int m0 = 0; m0 < NN; m0 += 32) {
    bf16x8 ar[4], br[2];
    br[0] = brp[0]; br[1] = brp[1];
    if (m0 + 32 < NN) {
#pragma unroll
      for (int bt = 0; bt < 2; bt++) {
        long vidx = (((long)((cw >> 4) + bt) * 128 + ((m0 + 32) >> 3) + g) * 16 + r) * 8;
        brp[bt] = *(const bf16x8*)(vbase + vidx);
      }
    }
#pragma unroll
    for (int rt = 0; rt < 4; rt++) {
      int prow = rt * 16 + r;
      int chunk = ((m0 >> 3) + g) ^ (prow & 7);
      ar[rt] = *(const bf16x8*)&ShBuf[prow * 1024 + chunk * 8];
    }
    __builtin_amdgcn_s_setprio(1);
#pragma unroll
    for (int rt = 0; rt < 4; rt++)
#pragma unroll
      for (int bt = 0; bt < 2; bt++)
        o[rt][bt] = __builtin_amdgcn_mfma_f32_16x16x32_bf16(ar[rt], br[bt], o[rt][bt], 0, 0, 0);
    __builtin_amdgcn_s_setprio(0);
  }

  // ---- epilogue: direct packed stores; block covers full 128B line per c ----
  unsigned short* obase = QKVt + (long)b * NN * CC;
#pragma unroll
  for (int rt = 0; rt < 4; rt++) {
#pragma unroll
    for (int bt = 0; bt < 2; bt++) {
      int c = cw + bt * 16 + r;
      int n = n0 + rt * 16 + g * 4;
      s16x4 pk;
      pk.x = (short)f2bf(o[rt][bt][0]);
      pk.y = (short)f2bf(o[rt][bt][1]);
      pk.z = (short)f2bf(o[rt][bt][2]);
      pk.w = (short)f2bf(o[rt][bt][3]);
      *(s16x4*)(obase + (long)c * NN + n) = pk;
    }
  }
}

extern "C" void kernel_launch(void* const* d_in, const int* in_sizes, int n_in,
                              void* d_out, int out_size, void* d_ws, size_t ws_size,
                              hipStream_t stream) {
  const float* x  = (const float*)d_in[0];
  const float* Wq = (const float*)d_in[1];
  const float* bq = (const float*)d_in[2];
  const float* Wk = (const float*)d_in[3];
  const float* bk = (const float*)d_in[4];
  const float* Wv = (const float*)d_in[5];
  const float* bv = (const float*)d_in[6];
  const float* Wp = (const float*)d_in[7];
  float* out = (float*)d_out;

  const long BNC = (long)BB * NN * CC;

  char* p = (char*)d_ws;
  unsigned short* Amat  = (unsigned short*)p; p += (long)NN * NN * 2;
  unsigned short* Qb    = (unsigned short*)p; p += BNC * 2;
  unsigned short* Ktb   = (unsigned short*)p; p += BNC * 2;   // tiled Kt
  unsigned short* Vtb   = (unsigned short*)p; p += BNC * 2;   // tiled V5
  unsigned short* QKVt  = (unsigned short*)p; p += BNC * 2;   // [b][c][n]

  // Fused QKV projection (inline f32->bf16) + Wp transpose (z==6 slice)
  gemm_qkv<<<dim3(BB, 8, 7), 256, 0, stream>>>(
      x, Wq, Wk, Wv, bq, bk, bv, Wp, Qb, Ktb, Vtb, Amat);

  // Fused softmax(QK^T)·V -> QKVt[c][n];  64 rows/block, 256 blocks = 1/CU
  attn_fused<<<dim3(BB, NN / 64), 512, 0, stream>>>(Qb, Ktb, Vtb, QKVt);

  // Z[hw][c] = sum_n Amat[hw][n] * QKVt[c][n] : M=1024, N=256, K=1024, f32 out
  gemm_tile<0, 1><<<dim3(BB, 8, 4), 256, 0, stream>>>(
      Amat, NN, 0L, QKVt, NN, (long)NN * CC, nullptr,
      out, CC, (long)NN * CC, NN);
}